// Round 3
// baseline (489.469 us; speedup 1.0000x reference)
//
#include <hip/hip_runtime.h>
#include <hip/hip_fp16.h>

#define NN 100000
#define NE 1600000

// ============================================================
// GEMM 1: H = x @ W  (f32 in, fp16 out) + attention-logit epilogue.
// block = 256 threads, M-tile = 64 rows, full N=128, K split in 2 passes.
// LDS: xs = A-tile transposed+swizzled [128k][64r] (32KB)
//      ws = B half-tile [64k][128c]               (32KB)
// thread (rg = tid>>4 rows rg*4..+3, tx = tid&15 cols tx*8..+7): acc[4][8]
// ============================================================

__global__ __launch_bounds__(256) void k_gemm_att(
    const float* __restrict__ A, const float* __restrict__ B,
    const float* __restrict__ att_s, const float* __restrict__ att_d,
    __half* __restrict__ Hh, float* __restrict__ as_out, float* __restrict__ ad_out,
    int M)
{
    __shared__ __align__(16) float xs[128 * 64];
    __shared__ __align__(16) float ws[64 * 128];
    int t = threadIdx.x;
    int row0 = blockIdx.x * 64;

    // stage A tile, transposed with XOR swizzle on 4-float groups
    {
        int r = t >> 2;
        int k0 = (t & 3) * 32;
        const float* ap = A + (size_t)(row0 + r) * 128 + k0;
        bool valid = (row0 + r) < M;
#pragma unroll
        for (int j = 0; j < 8; ++j) {
            float4 v = valid ? *(const float4*)(ap + j * 4) : make_float4(0.f, 0.f, 0.f, 0.f);
            int kb = k0 + j * 4;
            float vv[4] = {v.x, v.y, v.z, v.w};
#pragma unroll
            for (int m = 0; m < 4; ++m) {
                int kk = kb + m;
                int sw = (((r >> 2) ^ (kk & 15)) << 2) | (r & 3);
                xs[kk * 64 + sw] = vv[m];
            }
        }
    }

    int rg = t >> 4;
    int tx = t & 15;
    float acc[4][8];
#pragma unroll
    for (int i = 0; i < 4; ++i)
#pragma unroll
        for (int j = 0; j < 8; ++j) acc[i][j] = 0.f;

    for (int pass = 0; pass < 2; ++pass) {
        __syncthreads();
#pragma unroll
        for (int j = 0; j < 8; ++j) {
            int fi = j * 256 + t;
            int k = fi >> 5;
            int c4 = (fi & 31) * 4;
            *(float4*)(ws + k * 128 + c4) =
                *(const float4*)(B + (size_t)(pass * 64 + k) * 128 + c4);
        }
        __syncthreads();
#pragma unroll 4
        for (int kk = 0; kk < 64; ++kk) {
            int k = pass * 64 + kk;
            float4 a4 = *(const float4*)(xs + k * 64 + ((rg ^ (k & 15)) << 2));
            float4 b0 = *(const float4*)(ws + kk * 128 + tx * 8);
            float4 b1 = *(const float4*)(ws + kk * 128 + tx * 8 + 4);
            float av[4] = {a4.x, a4.y, a4.z, a4.w};
            float bv[8] = {b0.x, b0.y, b0.z, b0.w, b1.x, b1.y, b1.z, b1.w};
#pragma unroll
            for (int i = 0; i < 4; ++i)
#pragma unroll
                for (int j = 0; j < 8; ++j)
                    acc[i][j] = fmaf(av[i], bv[j], acc[i][j]);
        }
    }

    // write H rows in fp16
    int c0 = tx * 8;
#pragma unroll
    for (int i = 0; i < 4; ++i) {
        int row = row0 + rg * 4 + i;
        if (row < M) {
            __half2 ho[4];
#pragma unroll
            for (int k = 0; k < 4; ++k)
                ho[k] = __float22half2_rn(make_float2(acc[i][2 * k], acc[i][2 * k + 1]));
            *(float4*)(Hh + (size_t)row * 128 + c0) = *(float4*)ho;
        }
    }

    // attention logit epilogue: a_src[n][head] = sum_c h*att_src
    int head = tx >> 2;
    int cc = (tx & 3) * 8;
    float asv[8], adv[8];
#pragma unroll
    for (int j = 0; j < 8; ++j) {
        asv[j] = att_s[head * 32 + cc + j];
        adv[j] = att_d[head * 32 + cc + j];
    }
#pragma unroll
    for (int i = 0; i < 4; ++i) {
        float ps = 0.f, pd = 0.f;
#pragma unroll
        for (int j = 0; j < 8; ++j) {
            ps = fmaf(acc[i][j], asv[j], ps);
            pd = fmaf(acc[i][j], adv[j], pd);
        }
        ps += __shfl_xor(ps, 1); ps += __shfl_xor(ps, 2);
        pd += __shfl_xor(pd, 1); pd += __shfl_xor(pd, 2);
        int row = row0 + rg * 4 + i;
        if ((tx & 3) == 0 && row < M) {
            as_out[row * 4 + head] = ps;
            ad_out[row * 4 + head] = pd;
        }
    }
}

// ============================================================
// GEMM 2: Out = relu(P @ lin_w + b)  (fp16 A, f32 B/out)
// ============================================================

__global__ __launch_bounds__(256) void k_gemm_bias_relu(
    const __half* __restrict__ Ah, const float* __restrict__ B,
    const float* __restrict__ bias, float* __restrict__ Out, int M)
{
    __shared__ __align__(16) float xs[128 * 64];
    __shared__ __align__(16) float ws[64 * 128];
    int t = threadIdx.x;
    int row0 = blockIdx.x * 64;
    {
        int r = t >> 2;
        int k0 = (t & 3) * 32;
        const __half* ap = Ah + (size_t)(row0 + r) * 128 + k0;
        bool valid = (row0 + r) < M;
#pragma unroll
        for (int j = 0; j < 4; ++j) {
            float4 raw;
            if (valid) raw = *(const float4*)(ap + j * 8);
            else raw = make_float4(0.f, 0.f, 0.f, 0.f);
            __half2* ph = (__half2*)&raw;
            float f[8];
#pragma unroll
            for (int k = 0; k < 4; ++k) {
                float2 fp = __half22float2(ph[k]);
                f[2 * k] = fp.x; f[2 * k + 1] = fp.y;
            }
            if (!valid) { for (int k = 0; k < 8; ++k) f[k] = 0.f; }
#pragma unroll
            for (int m = 0; m < 8; ++m) {
                int kk = k0 + j * 8 + m;
                int sw = (((r >> 2) ^ (kk & 15)) << 2) | (r & 3);
                xs[kk * 64 + sw] = f[m];
            }
        }
    }
    int rg = t >> 4;
    int tx = t & 15;
    float acc[4][8];
#pragma unroll
    for (int i = 0; i < 4; ++i)
#pragma unroll
        for (int j = 0; j < 8; ++j) acc[i][j] = 0.f;

    for (int pass = 0; pass < 2; ++pass) {
        __syncthreads();
#pragma unroll
        for (int j = 0; j < 8; ++j) {
            int fi = j * 256 + t;
            int k = fi >> 5;
            int c4 = (fi & 31) * 4;
            *(float4*)(ws + k * 128 + c4) =
                *(const float4*)(B + (size_t)(pass * 64 + k) * 128 + c4);
        }
        __syncthreads();
#pragma unroll 4
        for (int kk = 0; kk < 64; ++kk) {
            int k = pass * 64 + kk;
            float4 a4 = *(const float4*)(xs + k * 64 + ((rg ^ (k & 15)) << 2));
            float4 b0 = *(const float4*)(ws + kk * 128 + tx * 8);
            float4 b1 = *(const float4*)(ws + kk * 128 + tx * 8 + 4);
            float av[4] = {a4.x, a4.y, a4.z, a4.w};
            float bv[8] = {b0.x, b0.y, b0.z, b0.w, b1.x, b1.y, b1.z, b1.w};
#pragma unroll
            for (int i = 0; i < 4; ++i)
#pragma unroll
                for (int j = 0; j < 8; ++j)
                    acc[i][j] = fmaf(av[i], bv[j], acc[i][j]);
        }
    }
    int c0 = tx * 8;
    float b0v[8];
#pragma unroll
    for (int j = 0; j < 8; ++j) b0v[j] = bias[c0 + j];
#pragma unroll
    for (int i = 0; i < 4; ++i) {
        int row = row0 + rg * 4 + i;
        if (row < M) {
            float o[8];
#pragma unroll
            for (int j = 0; j < 8; ++j) o[j] = fmaxf(acc[i][j] + b0v[j], 0.f);
            *(float4*)(Out + (size_t)row * 128 + c0) = make_float4(o[0], o[1], o[2], o[3]);
            *(float4*)(Out + (size_t)row * 128 + c0 + 4) = make_float4(o[4], o[5], o[6], o[7]);
        }
    }
}

// ============================================================
// CSR build
// ============================================================

__global__ void k_hist(const int* __restrict__ ei, int* __restrict__ deg, int E)
{
    int e = blockIdx.x * 256 + threadIdx.x;
    if (e < E) atomicAdd(&deg[ei[E + e]], 1);
}

__global__ __launch_bounds__(256) void k_scan1(
    const int* __restrict__ deg, int* __restrict__ off, int* __restrict__ bsum, int N)
{
    __shared__ int sd[256];
    int t = threadIdx.x;
    int base = blockIdx.x * 1024 + t * 4;
    int v[4];
#pragma unroll
    for (int m = 0; m < 4; ++m) v[m] = (base + m < N) ? deg[base + m] : 0;
    int tsum = v[0] + v[1] + v[2] + v[3];
    sd[t] = tsum;
    __syncthreads();
    for (int o = 1; o < 256; o <<= 1) {
        int x = (t >= o) ? sd[t - o] : 0;
        __syncthreads();
        sd[t] += x;
        __syncthreads();
    }
    int incl = sd[t];
    int p = incl - tsum;
#pragma unroll
    for (int m = 0; m < 4; ++m) {
        if (base + m < N) off[base + m] = p;
        p += v[m];
    }
    if (t == 255) bsum[blockIdx.x] = incl;
}

__global__ __launch_bounds__(128) void k_scan2(int* __restrict__ bsum, int nb)
{
    __shared__ int sd[128];
    int t = threadIdx.x;
    int v = (t < nb) ? bsum[t] : 0;
    sd[t] = v;
    __syncthreads();
    for (int o = 1; o < 128; o <<= 1) {
        int x = (t >= o) ? sd[t - o] : 0;
        __syncthreads();
        sd[t] += x;
        __syncthreads();
    }
    if (t < nb) bsum[t] = sd[t] - v;
}

// final offset fixup; also seeds cur[] with the running cursor so the
// CSR-fill kernel needs a single atomic and no extra off[] read.
__global__ void k_scan3(int* __restrict__ off, int* __restrict__ cur,
                        const int* __restrict__ bsum, int N)
{
    int i = blockIdx.x * 256 + threadIdx.x;
    if (i < N) {
        int o = off[i] + bsum[i >> 10];
        off[i] = o;
        cur[i] = o;
    }
}

// CSR fill: 4-byte scatter only. (Materializing exp-weights here caused
// ~100MB write-allocate fetch + ~110MB partial-line writeback — the exp
// moved to the gather's lane-parallel weight phase instead.)
__global__ void k_csr(const int* __restrict__ ei, int* __restrict__ cur,
                      int* __restrict__ csr, int E)
{
    int e = blockIdx.x * 256 + threadIdx.x;
    if (e < E) {
        int s = ei[e];
        int d = ei[E + e];
        int p = atomicAdd(&cur[d], 1);
        csr[p] = s;
    }
}

// ============================================================
// Gather/accumulate: one wave per destination node.
// Weight phase (lane-parallel, 1 edge/lane): gather as_[src], add wave-
// uniform ad_[n], leaky+exp (4 per edge TOTAL), stash in LDS.
// Main loop: 4 edges/iter, 16 lanes x 8 fp16 channels per edge.
// Normalize by the softmax denominator at the end.
// ============================================================

__global__ __launch_bounds__(256) void k_gather(
    const __half* __restrict__ Hh, const float* __restrict__ as_,
    const float* __restrict__ ad_, const int* __restrict__ off,
    const int* __restrict__ deg, const int* __restrict__ csr,
    __half* __restrict__ P, int N)
{
    __shared__ float ex_s[4][256];
    __shared__ int src_s[4][64];
    int wid = threadIdx.x >> 6;
    int lane = threadIdx.x & 63;
    int n = blockIdx.x * 4 + wid;
    if (n >= N) return;
    int dg = deg[n];
    int base = off[n];
    float4 adn = *(const float4*)(ad_ + (size_t)n * 4);
    int g = lane >> 4;        // edge sub-slot 0..3
    int li = lane & 15;       // channel group: channels li*8 .. li*8+7
    int hh = li >> 2;         // head of this channel group
    float s0 = 0.f, s1 = 0.f, s2 = 0.f, s3 = 0.f;
    float acc[8] = {0.f, 0.f, 0.f, 0.f, 0.f, 0.f, 0.f, 0.f};

    for (int c0 = 0; c0 < dg; c0 += 64) {
        int cnt = min(64, dg - c0);
        if (lane < cnt) {
            int se = csr[base + c0 + lane];
            float4 as = *(const float4*)(as_ + (size_t)se * 4);
            float e0 = as.x + adn.x, e1 = as.y + adn.y;
            float e2 = as.z + adn.z, e3 = as.w + adn.w;
            e0 = fmaxf(e0, 0.2f * e0); e1 = fmaxf(e1, 0.2f * e1);
            e2 = fmaxf(e2, 0.2f * e2); e3 = fmaxf(e3, 0.2f * e3);
            float x0 = __expf(e0), x1 = __expf(e1);
            float x2 = __expf(e2), x3 = __expf(e3);
            s0 += x0; s1 += x1; s2 += x2; s3 += x3;
            *(float4*)&ex_s[wid][lane * 4] = make_float4(x0, x1, x2, x3);
            src_s[wid][lane] = se;
        }
        __asm__ volatile("s_waitcnt lgkmcnt(0)" ::: "memory");
        int iters = (cnt + 3) >> 2;
        for (int ii = 0; ii < iters; ++ii) {
            int j = ii * 4 + g;
            bool valid = j < cnt;
            float w = valid ? ex_s[wid][j * 4 + hh] : 0.f;
            int se = valid ? src_s[wid][j] : 0;
            float4 raw = *(const float4*)(Hh + (size_t)se * 128 + li * 8);
            __half2* ph = (__half2*)&raw;
            float2 f0 = __half22float2(ph[0]);
            float2 f1 = __half22float2(ph[1]);
            float2 f2 = __half22float2(ph[2]);
            float2 f3 = __half22float2(ph[3]);
            acc[0] = fmaf(w, f0.x, acc[0]);
            acc[1] = fmaf(w, f0.y, acc[1]);
            acc[2] = fmaf(w, f1.x, acc[2]);
            acc[3] = fmaf(w, f1.y, acc[3]);
            acc[4] = fmaf(w, f2.x, acc[4]);
            acc[5] = fmaf(w, f2.y, acc[5]);
            acc[6] = fmaf(w, f3.x, acc[6]);
            acc[7] = fmaf(w, f3.y, acc[7]);
        }
        __asm__ volatile("s_waitcnt lgkmcnt(0)" ::: "memory");
    }

    // total softmax denominators (each lane holds partials from weight phase)
#pragma unroll
    for (int o = 1; o < 64; o <<= 1) {
        s0 += __shfl_xor(s0, o);
        s1 += __shfl_xor(s1, o);
        s2 += __shfl_xor(s2, o);
        s3 += __shfl_xor(s3, o);
    }
    // combine the 4 edge sub-slots (lanes sharing li)
#pragma unroll
    for (int o = 16; o < 64; o <<= 1)
#pragma unroll
        for (int c = 0; c < 8; ++c) acc[c] += __shfl_xor(acc[c], o);

    float sh = (hh == 0) ? s0 : (hh == 1) ? s1 : (hh == 2) ? s2 : s3;
    float inv = 1.f / (sh + 1e-16f);
    if (g == 0) {
        __half2 o4[4];
#pragma unroll
        for (int k = 0; k < 4; ++k)
            o4[k] = __float22half2_rn(make_float2(acc[2 * k] * inv, acc[2 * k + 1] * inv));
        *(float4*)(P + (size_t)n * 128 + li * 8) = *(float4*)o4;
    }
}

// ============================================================

extern "C" void kernel_launch(void* const* d_in, const int* in_sizes, int n_in,
                              void* d_out, int out_size, void* d_ws, size_t ws_size,
                              hipStream_t stream)
{
    const float* x     = (const float*)d_in[0];
    const int*   ei    = (const int*)d_in[1];
    const float* W     = (const float*)d_in[2];
    const float* att_s = (const float*)d_in[3];
    const float* att_d = (const float*)d_in[4];
    const float* lin_w = (const float*)d_in[5];
    const float* lin_b = (const float*)d_in[6];
    float* out = (float*)d_out;
    int N = in_sizes[0] / 128;
    int E = in_sizes[1] / 2;

    char* p = (char*)d_ws;
    auto alloc = [&](size_t bytes) { char* r = p; p += (bytes + 255) & ~(size_t)255; return r; };
    __half* Hh  = (__half*)alloc((size_t)N * 128 * 2);
    __half* P   = (__half*)alloc((size_t)N * 128 * 2);
    float* AS   = (float*)alloc((size_t)N * 4 * 4);
    float* AD   = (float*)alloc((size_t)N * 4 * 4);
    int*   deg  = (int*)alloc((size_t)N * 4);
    int*   cur  = (int*)alloc((size_t)N * 4);
    int*   off  = (int*)alloc((size_t)N * 4);
    int*   bsum = (int*)alloc(4096);
    int*   csr  = (int*)alloc((size_t)E * 4);

    hipMemsetAsync(deg, 0, (size_t)N * 4, stream);

    int mb = (N + 63) / 64;
    k_gemm_att<<<mb, 256, 0, stream>>>(x, W, att_s, att_d, Hh, AS, AD, N);
    k_hist<<<(E + 255) / 256, 256, 0, stream>>>(ei, deg, E);
    int nb1 = (N + 1023) / 1024;
    k_scan1<<<nb1, 256, 0, stream>>>(deg, off, bsum, N);
    k_scan2<<<1, 128, 0, stream>>>(bsum, nb1);
    k_scan3<<<(N + 255) / 256, 256, 0, stream>>>(off, cur, bsum, N);
    k_csr<<<(E + 255) / 256, 256, 0, stream>>>(ei, cur, csr, E);
    k_gather<<<(N + 3) / 4, 256, 0, stream>>>(Hh, AS, AD, off, deg, csr, P, N);
    k_gemm_bias_relu<<<mb, 256, 0, stream>>>(P, lin_w, lin_b, out, N);
}

// Round 4
// 358.912 us; speedup vs baseline: 1.3638x; 1.3638x over previous
//
#include <hip/hip_runtime.h>
#include <hip/hip_fp16.h>

#define NB   256   // dst buckets (512 nodes each), bucket = dst >> 9
#define NBLK 256   // blocks in phases A/C
#define BSH  9

// ============================================================
// GEMM 1: H = x @ W  (f32 in, fp16 out) + attention-logit epilogue.
// ============================================================

__global__ __launch_bounds__(256) void k_gemm_att(
    const float* __restrict__ A, const float* __restrict__ B,
    const float* __restrict__ att_s, const float* __restrict__ att_d,
    __half* __restrict__ Hh, float* __restrict__ as_out, float* __restrict__ ad_out,
    int M)
{
    __shared__ __align__(16) float xs[128 * 64];
    __shared__ __align__(16) float ws[64 * 128];
    int t = threadIdx.x;
    int row0 = blockIdx.x * 64;

    {
        int r = t >> 2;
        int k0 = (t & 3) * 32;
        const float* ap = A + (size_t)(row0 + r) * 128 + k0;
        bool valid = (row0 + r) < M;
#pragma unroll
        for (int j = 0; j < 8; ++j) {
            float4 v = valid ? *(const float4*)(ap + j * 4) : make_float4(0.f, 0.f, 0.f, 0.f);
            int kb = k0 + j * 4;
            float vv[4] = {v.x, v.y, v.z, v.w};
#pragma unroll
            for (int m = 0; m < 4; ++m) {
                int kk = kb + m;
                int sw = (((r >> 2) ^ (kk & 15)) << 2) | (r & 3);
                xs[kk * 64 + sw] = vv[m];
            }
        }
    }

    int rg = t >> 4;
    int tx = t & 15;
    float acc[4][8];
#pragma unroll
    for (int i = 0; i < 4; ++i)
#pragma unroll
        for (int j = 0; j < 8; ++j) acc[i][j] = 0.f;

    for (int pass = 0; pass < 2; ++pass) {
        __syncthreads();
#pragma unroll
        for (int j = 0; j < 8; ++j) {
            int fi = j * 256 + t;
            int k = fi >> 5;
            int c4 = (fi & 31) * 4;
            *(float4*)(ws + k * 128 + c4) =
                *(const float4*)(B + (size_t)(pass * 64 + k) * 128 + c4);
        }
        __syncthreads();
#pragma unroll 4
        for (int kk = 0; kk < 64; ++kk) {
            int k = pass * 64 + kk;
            float4 a4 = *(const float4*)(xs + k * 64 + ((rg ^ (k & 15)) << 2));
            float4 b0 = *(const float4*)(ws + kk * 128 + tx * 8);
            float4 b1 = *(const float4*)(ws + kk * 128 + tx * 8 + 4);
            float av[4] = {a4.x, a4.y, a4.z, a4.w};
            float bv[8] = {b0.x, b0.y, b0.z, b0.w, b1.x, b1.y, b1.z, b1.w};
#pragma unroll
            for (int i = 0; i < 4; ++i)
#pragma unroll
                for (int j = 0; j < 8; ++j)
                    acc[i][j] = fmaf(av[i], bv[j], acc[i][j]);
        }
    }

    int c0 = tx * 8;
#pragma unroll
    for (int i = 0; i < 4; ++i) {
        int row = row0 + rg * 4 + i;
        if (row < M) {
            __half2 ho[4];
#pragma unroll
            for (int k = 0; k < 4; ++k)
                ho[k] = __float22half2_rn(make_float2(acc[i][2 * k], acc[i][2 * k + 1]));
            *(float4*)(Hh + (size_t)row * 128 + c0) = *(float4*)ho;
        }
    }

    int head = tx >> 2;
    int cc = (tx & 3) * 8;
    float asv[8], adv[8];
#pragma unroll
    for (int j = 0; j < 8; ++j) {
        asv[j] = att_s[head * 32 + cc + j];
        adv[j] = att_d[head * 32 + cc + j];
    }
#pragma unroll
    for (int i = 0; i < 4; ++i) {
        float ps = 0.f, pd = 0.f;
#pragma unroll
        for (int j = 0; j < 8; ++j) {
            ps = fmaf(acc[i][j], asv[j], ps);
            pd = fmaf(acc[i][j], adv[j], pd);
        }
        ps += __shfl_xor(ps, 1); ps += __shfl_xor(ps, 2);
        pd += __shfl_xor(pd, 1); pd += __shfl_xor(pd, 2);
        int row = row0 + rg * 4 + i;
        if ((tx & 3) == 0 && row < M) {
            as_out[row * 4 + head] = ps;
            ad_out[row * 4 + head] = pd;
        }
    }
}

// ============================================================
// GEMM 2: Out = relu(P @ lin_w + b)  (fp16 A, f32 B/out)
// ============================================================

__global__ __launch_bounds__(256) void k_gemm_bias_relu(
    const __half* __restrict__ Ah, const float* __restrict__ B,
    const float* __restrict__ bias, float* __restrict__ Out, int M)
{
    __shared__ __align__(16) float xs[128 * 64];
    __shared__ __align__(16) float ws[64 * 128];
    int t = threadIdx.x;
    int row0 = blockIdx.x * 64;
    {
        int r = t >> 2;
        int k0 = (t & 3) * 32;
        const __half* ap = Ah + (size_t)(row0 + r) * 128 + k0;
        bool valid = (row0 + r) < M;
#pragma unroll
        for (int j = 0; j < 4; ++j) {
            float4 raw;
            if (valid) raw = *(const float4*)(ap + j * 8);
            else raw = make_float4(0.f, 0.f, 0.f, 0.f);
            __half2* ph = (__half2*)&raw;
            float f[8];
#pragma unroll
            for (int k = 0; k < 4; ++k) {
                float2 fp = __half22float2(ph[k]);
                f[2 * k] = fp.x; f[2 * k + 1] = fp.y;
            }
            if (!valid) { for (int k = 0; k < 8; ++k) f[k] = 0.f; }
#pragma unroll
            for (int m = 0; m < 8; ++m) {
                int kk = k0 + j * 8 + m;
                int sw = (((r >> 2) ^ (kk & 15)) << 2) | (r & 3);
                xs[kk * 64 + sw] = f[m];
            }
        }
    }
    int rg = t >> 4;
    int tx = t & 15;
    float acc[4][8];
#pragma unroll
    for (int i = 0; i < 4; ++i)
#pragma unroll
        for (int j = 0; j < 8; ++j) acc[i][j] = 0.f;

    for (int pass = 0; pass < 2; ++pass) {
        __syncthreads();
#pragma unroll
        for (int j = 0; j < 8; ++j) {
            int fi = j * 256 + t;
            int k = fi >> 5;
            int c4 = (fi & 31) * 4;
            *(float4*)(ws + k * 128 + c4) =
                *(const float4*)(B + (size_t)(pass * 64 + k) * 128 + c4);
        }
        __syncthreads();
#pragma unroll 4
        for (int kk = 0; kk < 64; ++kk) {
            int k = pass * 64 + kk;
            float4 a4 = *(const float4*)(xs + k * 64 + ((rg ^ (k & 15)) << 2));
            float4 b0 = *(const float4*)(ws + kk * 128 + tx * 8);
            float4 b1 = *(const float4*)(ws + kk * 128 + tx * 8 + 4);
            float av[4] = {a4.x, a4.y, a4.z, a4.w};
            float bv[8] = {b0.x, b0.y, b0.z, b0.w, b1.x, b1.y, b1.z, b1.w};
#pragma unroll
            for (int i = 0; i < 4; ++i)
#pragma unroll
                for (int j = 0; j < 8; ++j)
                    acc[i][j] = fmaf(av[i], bv[j], acc[i][j]);
        }
    }
    int c0 = tx * 8;
    float b0v[8];
#pragma unroll
    for (int j = 0; j < 8; ++j) b0v[j] = bias[c0 + j];
#pragma unroll
    for (int i = 0; i < 4; ++i) {
        int row = row0 + rg * 4 + i;
        if (row < M) {
            float o[8];
#pragma unroll
            for (int j = 0; j < 8; ++j) o[j] = fmaxf(acc[i][j] + b0v[j], 0.f);
            *(float4*)(Out + (size_t)row * 128 + c0) = make_float4(o[0], o[1], o[2], o[3]);
            *(float4*)(Out + (size_t)row * 128 + c0 + 4) = make_float4(o[4], o[5], o[6], o[7]);
        }
    }
}

// ============================================================
// CSR build, atomic-free at global scope (counting sort, 2 levels).
// Bucket = dst >> 9 (512 nodes). bh layout: bh[bucket * NBLK + block].
// ============================================================

// Phase A: per-block bucket histogram (LDS atomics only)
__global__ __launch_bounds__(256) void k_ph_hist(
    const int* __restrict__ dst, int* __restrict__ bh, int E, int chunk)
{
    __shared__ int hist[NB];
    int t = threadIdx.x;
    hist[t] = 0;
    __syncthreads();
    int e0 = blockIdx.x * chunk;
    int e1 = min(e0 + chunk, E);
    for (int e = e0 + t; e < e1; e += 256)
        atomicAdd(&hist[dst[e] >> BSH], 1);
    __syncthreads();
    bh[t * NBLK + blockIdx.x] = hist[t];
}

// Phase B: flat exclusive scan of NB*NBLK ints (bucket-major), one block.
__global__ __launch_bounds__(1024) void k_ph_scan(int* __restrict__ bh)
{
    __shared__ int sd[1024];
    const int per = (NB * NBLK) / 1024;  // 64
    int t = threadIdx.x;
    int base = t * per;
    int loc[per];
    int sum = 0;
#pragma unroll
    for (int j = 0; j < per; ++j) { loc[j] = bh[base + j]; sum += loc[j]; }
    sd[t] = sum;
    __syncthreads();
    for (int o = 1; o < 1024; o <<= 1) {
        int x = (t >= o) ? sd[t - o] : 0;
        __syncthreads();
        sd[t] += x;
        __syncthreads();
    }
    int run = sd[t] - sum;
#pragma unroll
    for (int j = 0; j < per; ++j) { bh[base + j] = run; run += loc[j]; }
}

// Phase C: scatter (src,dst) pairs into per-(bucket,block) private segments.
// No global atomics; each block's write regions are disjoint from all others.
__global__ __launch_bounds__(256) void k_ph_bin(
    const int* __restrict__ ei, const int* __restrict__ bh,
    int2* __restrict__ binned, int E, int chunk)
{
    __shared__ int boff[NB];
    int t = threadIdx.x;
    boff[t] = bh[t * NBLK + blockIdx.x];
    __syncthreads();
    int e0 = blockIdx.x * chunk;
    int e1 = min(e0 + chunk, E);
    for (int e = e0 + t; e < e1; e += 256) {
        int s = ei[e];
        int d = ei[E + e];
        int p = atomicAdd(&boff[d >> BSH], 1);  // LDS atomic
        binned[p] = make_int2(s, d);
    }
}

// Phase D: per-bucket counting sort -> csr slice + off/deg (coalesced).
// All scatter confined to one workgroup's ~32KB segment (single XCD L2).
__global__ __launch_bounds__(256) void k_ph_csr(
    const int2* __restrict__ binned, const int* __restrict__ bh,
    int* __restrict__ csr, int* __restrict__ off, int* __restrict__ deg,
    int N, int E)
{
    __shared__ int cnt[512], loff[512], sd[256];
    int b = blockIdx.x;
    int lo = b << BSH;
    if (lo >= N) return;
    int t = threadIdx.x;
    int seg = bh[b * NBLK];
    int segend = (b + 1 < NB) ? bh[(b + 1) * NBLK] : E;
    int len = segend - seg;
    cnt[t] = 0; cnt[t + 256] = 0;
    __syncthreads();
    for (int i = t; i < len; i += 256)
        atomicAdd(&cnt[binned[seg + i].y - lo], 1);
    __syncthreads();
    int a0 = cnt[2 * t], a1 = cnt[2 * t + 1];
    int s = a0 + a1;
    sd[t] = s;
    __syncthreads();
    for (int o = 1; o < 256; o <<= 1) {
        int x = (t >= o) ? sd[t - o] : 0;
        __syncthreads();
        sd[t] += x;
        __syncthreads();
    }
    int ex = sd[t] - s;
    loff[2 * t] = ex;
    loff[2 * t + 1] = ex + a0;
    int n0 = lo + 2 * t;
    if (n0 < N)     { off[n0] = seg + ex;          deg[n0] = a0; }
    if (n0 + 1 < N) { off[n0 + 1] = seg + ex + a0; deg[n0 + 1] = a1; }
    __syncthreads();
    for (int i = t; i < len; i += 256) {
        int2 e = binned[seg + i];
        int p = atomicAdd(&loff[e.y - lo], 1);  // LDS atomic
        csr[seg + p] = e.x;
    }
}

// ============================================================
// Gather/accumulate: one wave per destination node (unchanged).
// ============================================================

__global__ __launch_bounds__(256) void k_gather(
    const __half* __restrict__ Hh, const float* __restrict__ as_,
    const float* __restrict__ ad_, const int* __restrict__ off,
    const int* __restrict__ deg, const int* __restrict__ csr,
    __half* __restrict__ P, int N)
{
    __shared__ float ex_s[4][256];
    __shared__ int src_s[4][64];
    int wid = threadIdx.x >> 6;
    int lane = threadIdx.x & 63;
    int n = blockIdx.x * 4 + wid;
    if (n >= N) return;
    int dg = deg[n];
    int base = off[n];
    float4 adn = *(const float4*)(ad_ + (size_t)n * 4);
    int g = lane >> 4;
    int li = lane & 15;
    int hh = li >> 2;
    float s0 = 0.f, s1 = 0.f, s2 = 0.f, s3 = 0.f;
    float acc[8] = {0.f, 0.f, 0.f, 0.f, 0.f, 0.f, 0.f, 0.f};

    for (int c0 = 0; c0 < dg; c0 += 64) {
        int cnt = min(64, dg - c0);
        if (lane < cnt) {
            int se = csr[base + c0 + lane];
            float4 as = *(const float4*)(as_ + (size_t)se * 4);
            float e0 = as.x + adn.x, e1 = as.y + adn.y;
            float e2 = as.z + adn.z, e3 = as.w + adn.w;
            e0 = fmaxf(e0, 0.2f * e0); e1 = fmaxf(e1, 0.2f * e1);
            e2 = fmaxf(e2, 0.2f * e2); e3 = fmaxf(e3, 0.2f * e3);
            float x0 = __expf(e0), x1 = __expf(e1);
            float x2 = __expf(e2), x3 = __expf(e3);
            s0 += x0; s1 += x1; s2 += x2; s3 += x3;
            *(float4*)&ex_s[wid][lane * 4] = make_float4(x0, x1, x2, x3);
            src_s[wid][lane] = se;
        }
        __asm__ volatile("s_waitcnt lgkmcnt(0)" ::: "memory");
        int iters = (cnt + 3) >> 2;
        for (int ii = 0; ii < iters; ++ii) {
            int j = ii * 4 + g;
            bool valid = j < cnt;
            float w = valid ? ex_s[wid][j * 4 + hh] : 0.f;
            int se = valid ? src_s[wid][j] : 0;
            float4 raw = *(const float4*)(Hh + (size_t)se * 128 + li * 8);
            __half2* ph = (__half2*)&raw;
            float2 f0 = __half22float2(ph[0]);
            float2 f1 = __half22float2(ph[1]);
            float2 f2 = __half22float2(ph[2]);
            float2 f3 = __half22float2(ph[3]);
            acc[0] = fmaf(w, f0.x, acc[0]);
            acc[1] = fmaf(w, f0.y, acc[1]);
            acc[2] = fmaf(w, f1.x, acc[2]);
            acc[3] = fmaf(w, f1.y, acc[3]);
            acc[4] = fmaf(w, f2.x, acc[4]);
            acc[5] = fmaf(w, f2.y, acc[5]);
            acc[6] = fmaf(w, f3.x, acc[6]);
            acc[7] = fmaf(w, f3.y, acc[7]);
        }
        __asm__ volatile("s_waitcnt lgkmcnt(0)" ::: "memory");
    }

#pragma unroll
    for (int o = 1; o < 64; o <<= 1) {
        s0 += __shfl_xor(s0, o);
        s1 += __shfl_xor(s1, o);
        s2 += __shfl_xor(s2, o);
        s3 += __shfl_xor(s3, o);
    }
#pragma unroll
    for (int o = 16; o < 64; o <<= 1)
#pragma unroll
        for (int c = 0; c < 8; ++c) acc[c] += __shfl_xor(acc[c], o);

    float sh = (hh == 0) ? s0 : (hh == 1) ? s1 : (hh == 2) ? s2 : s3;
    float inv = 1.f / (sh + 1e-16f);
    if (g == 0) {
        __half2 o4[4];
#pragma unroll
        for (int k = 0; k < 4; ++k)
            o4[k] = __float22half2_rn(make_float2(acc[2 * k] * inv, acc[2 * k + 1] * inv));
        *(float4*)(P + (size_t)n * 128 + li * 8) = *(float4*)o4;
    }
}

// ============================================================

extern "C" void kernel_launch(void* const* d_in, const int* in_sizes, int n_in,
                              void* d_out, int out_size, void* d_ws, size_t ws_size,
                              hipStream_t stream)
{
    const float* x     = (const float*)d_in[0];
    const int*   ei    = (const int*)d_in[1];
    const float* W     = (const float*)d_in[2];
    const float* att_s = (const float*)d_in[3];
    const float* att_d = (const float*)d_in[4];
    const float* lin_w = (const float*)d_in[5];
    const float* lin_b = (const float*)d_in[6];
    float* out = (float*)d_out;
    int N = in_sizes[0] / 128;
    int E = in_sizes[1] / 2;

    char* p = (char*)d_ws;
    auto alloc = [&](size_t bytes) { char* r = p; p += (bytes + 255) & ~(size_t)255; return r; };
    __half* Hh   = (__half*)alloc((size_t)N * 128 * 2);
    __half* P    = (__half*)alloc((size_t)N * 128 * 2);
    float*  AS   = (float*)alloc((size_t)N * 4 * 4);
    float*  AD   = (float*)alloc((size_t)N * 4 * 4);
    int*    deg  = (int*)alloc((size_t)N * 4);
    int*    off  = (int*)alloc((size_t)N * 4);
    int*    csr  = (int*)alloc((size_t)E * 4);
    int2*   binned = (int2*)alloc((size_t)E * 8);
    int*    bh   = (int*)alloc((size_t)NB * NBLK * 4);

    int chunk = (E + NBLK - 1) / NBLK;
    int mb = (N + 63) / 64;
    k_gemm_att<<<mb, 256, 0, stream>>>(x, W, att_s, att_d, Hh, AS, AD, N);
    k_ph_hist<<<NBLK, 256, 0, stream>>>(ei + E, bh, E, chunk);
    k_ph_scan<<<1, 1024, 0, stream>>>(bh);
    k_ph_bin<<<NBLK, 256, 0, stream>>>(ei, bh, binned, E, chunk);
    k_ph_csr<<<NB, 256, 0, stream>>>(binned, bh, csr, off, deg, N, E);
    k_gather<<<(N + 3) / 4, 256, 0, stream>>>(Hh, AS, AD, off, deg, csr, P, N);
    k_gemm_bias_relu<<<mb, 256, 0, stream>>>(P, lin_w, lin_b, out, N);
}

// Round 5
// 304.665 us; speedup vs baseline: 1.6066x; 1.1781x over previous
//
#include <hip/hip_runtime.h>
#include <hip/hip_fp16.h>

#define NB   256   // dst buckets (512 nodes each), bucket = dst >> 9
#define NBLK 256   // blocks in phases A/C
#define BSH  9

typedef _Float16 f16;
typedef _Float16 half8 __attribute__((ext_vector_type(8)));
typedef float f32x4 __attribute__((ext_vector_type(4)));

// ============================================================
// MFMA GEMM 1: H = x @ W (f32 in -> fp16 compute, f32 acc, fp16 out)
// + attention-logit epilogue (a_src/a_dst per node/head).
// Block: 256 thr = 4 waves, tile 64x128, K=128.
// Wave w: rows (w&1)*32..+31, cols (w>>1)*64..+63 -> acc[2][4] 16x16 tiles.
// LDS: as_lds [m][k] f16 stride 136; bs_lds [n][k] f16 stride 136 (W transposed).
// MFMA frag maps (m89/m120-verified): A[m=lane&15][k=quad*8+j],
// B[k=quad*8+j][n=lane&15], C/D col=lane&15 row=quad*4+reg.
// ============================================================

__global__ __launch_bounds__(256) void k_gemm_att(
    const float* __restrict__ A, const float* __restrict__ B,
    const float* __restrict__ att_s, const float* __restrict__ att_d,
    f16* __restrict__ Hh, float* __restrict__ as_out, float* __restrict__ ad_out,
    int M)
{
    __shared__ __align__(16) f16 as_lds[64 * 136];
    __shared__ __align__(16) f16 bs_lds[128 * 136];
    int t = threadIdx.x;
    int row0 = blockIdx.x * 64;

    // Stage A: x rows f32 -> f16, [m][k]
    {
        int r = t >> 2;
        int kq = (t & 3) * 32;
        const float* ap = A + (size_t)(row0 + r) * 128 + kq;
        bool valid = (row0 + r) < M;
        f16* dst = as_lds + r * 136 + kq;
#pragma unroll
        for (int j = 0; j < 8; ++j) {
            float4 v = valid ? *(const float4*)(ap + j * 4) : make_float4(0.f, 0.f, 0.f, 0.f);
            dst[j * 4 + 0] = (f16)v.x; dst[j * 4 + 1] = (f16)v.y;
            dst[j * 4 + 2] = (f16)v.z; dst[j * 4 + 3] = (f16)v.w;
        }
    }
    // Stage B: W [k][n] f32 -> bs_lds [n][k] f16 (transpose)
    {
        int k = t >> 1;
        int n0 = (t & 1) * 64;
        const float* bp = B + (size_t)k * 128 + n0;
#pragma unroll
        for (int j = 0; j < 16; ++j) {
            float4 v = *(const float4*)(bp + j * 4);
            bs_lds[(n0 + j * 4 + 0) * 136 + k] = (f16)v.x;
            bs_lds[(n0 + j * 4 + 1) * 136 + k] = (f16)v.y;
            bs_lds[(n0 + j * 4 + 2) * 136 + k] = (f16)v.z;
            bs_lds[(n0 + j * 4 + 3) * 136 + k] = (f16)v.w;
        }
    }
    __syncthreads();

    int w = t >> 6, ln = t & 63;
    int rr = (w & 1) * 32;
    int cc = (w >> 1) * 64;
    int q = ln >> 4, m = ln & 15;

    f32x4 acc[2][4];
#pragma unroll
    for (int i = 0; i < 2; ++i)
#pragma unroll
        for (int j = 0; j < 4; ++j) acc[i][j] = (f32x4){0.f, 0.f, 0.f, 0.f};

#pragma unroll
    for (int ks = 0; ks < 4; ++ks) {
        int k0 = ks * 32 + q * 8;
        half8 a0 = *(const half8*)(as_lds + (rr + m) * 136 + k0);
        half8 a1 = *(const half8*)(as_lds + (rr + 16 + m) * 136 + k0);
        half8 bf[4];
#pragma unroll
        for (int j = 0; j < 4; ++j)
            bf[j] = *(const half8*)(bs_lds + (cc + j * 16 + m) * 136 + k0);
#pragma unroll
        for (int j = 0; j < 4; ++j) {
            acc[0][j] = __builtin_amdgcn_mfma_f32_16x16x32_f16(a0, bf[j], acc[0][j], 0, 0, 0);
            acc[1][j] = __builtin_amdgcn_mfma_f32_16x16x32_f16(a1, bf[j], acc[1][j], 0, 0, 0);
        }
    }
    __syncthreads();
    // acc -> ep tile (reuse as_lds) [row][col] f16 stride 136
#pragma unroll
    for (int i = 0; i < 2; ++i)
#pragma unroll
        for (int j = 0; j < 4; ++j)
#pragma unroll
            for (int g = 0; g < 4; ++g)
                as_lds[(rr + i * 16 + q * 4 + g) * 136 + cc + j * 16 + m] = (f16)acc[i][j][g];
    __syncthreads();
    // coalesced H write
    {
        int r = t >> 2, cq = (t & 3) * 32;
        if (row0 + r < M) {
            float4 o0 = *(const float4*)(as_lds + r * 136 + cq);
            float4 o1 = *(const float4*)(as_lds + r * 136 + cq + 8);
            float4 o2 = *(const float4*)(as_lds + r * 136 + cq + 16);
            float4 o3 = *(const float4*)(as_lds + r * 136 + cq + 24);
            float4* hp = (float4*)(Hh + (size_t)(row0 + r) * 128 + cq);
            hp[0] = o0; hp[1] = o1; hp[2] = o2; hp[3] = o3;
        }
    }
    // attention dots: wave w rows w*16..+15; lane (q,m): row w*16+m, head q
    {
        int rl = w * 16 + m;
        int head = q;
        float ds = 0.f, dd = 0.f;
#pragma unroll
        for (int ch = 0; ch < 4; ++ch) {
            half8 hv = *(const half8*)(as_lds + rl * 136 + head * 32 + ch * 8);
            float4 s0 = *(const float4*)(att_s + head * 32 + ch * 8);
            float4 s1 = *(const float4*)(att_s + head * 32 + ch * 8 + 4);
            float4 d0 = *(const float4*)(att_d + head * 32 + ch * 8);
            float4 d1 = *(const float4*)(att_d + head * 32 + ch * 8 + 4);
            ds += (float)hv[0] * s0.x + (float)hv[1] * s0.y + (float)hv[2] * s0.z + (float)hv[3] * s0.w
                + (float)hv[4] * s1.x + (float)hv[5] * s1.y + (float)hv[6] * s1.z + (float)hv[7] * s1.w;
            dd += (float)hv[0] * d0.x + (float)hv[1] * d0.y + (float)hv[2] * d0.z + (float)hv[3] * d0.w
                + (float)hv[4] * d1.x + (float)hv[5] * d1.y + (float)hv[6] * d1.z + (float)hv[7] * d1.w;
        }
        if (row0 + rl < M) {
            as_out[(row0 + rl) * 4 + head] = ds;
            ad_out[(row0 + rl) * 4 + head] = dd;
        }
    }
}

// ============================================================
// MFMA GEMM 2: Out = relu(P @ lin_w + b) (fp16 A, f32 B -> f16, f32 out)
// ============================================================

__global__ __launch_bounds__(256) void k_gemm_bias_relu(
    const f16* __restrict__ Ah, const float* __restrict__ B,
    const float* __restrict__ bias, float* __restrict__ Out, int M)
{
    __shared__ __align__(16) f16 as_lds[64 * 136];
    __shared__ __align__(16) f16 bs_lds[128 * 136];
    int t = threadIdx.x;
    int row0 = blockIdx.x * 64;

    // Stage A: P fp16 rows, direct copy
    {
        int r = t >> 2;
        int kq = (t & 3) * 32;
        f16* dst = as_lds + r * 136 + kq;
        if (row0 + r < M) {
            const float4* ap = (const float4*)(Ah + (size_t)(row0 + r) * 128 + kq);
#pragma unroll
            for (int j = 0; j < 4; ++j) *(float4*)(dst + j * 8) = ap[j];
        } else {
#pragma unroll
            for (int j = 0; j < 32; ++j) dst[j] = (f16)0.f;
        }
    }
    // Stage B: lin_w [k][n] f32 -> [n][k] f16
    {
        int k = t >> 1;
        int n0 = (t & 1) * 64;
        const float* bp = B + (size_t)k * 128 + n0;
#pragma unroll
        for (int j = 0; j < 16; ++j) {
            float4 v = *(const float4*)(bp + j * 4);
            bs_lds[(n0 + j * 4 + 0) * 136 + k] = (f16)v.x;
            bs_lds[(n0 + j * 4 + 1) * 136 + k] = (f16)v.y;
            bs_lds[(n0 + j * 4 + 2) * 136 + k] = (f16)v.z;
            bs_lds[(n0 + j * 4 + 3) * 136 + k] = (f16)v.w;
        }
    }
    __syncthreads();

    int w = t >> 6, ln = t & 63;
    int rr = (w & 1) * 32;
    int cc = (w >> 1) * 64;
    int q = ln >> 4, m = ln & 15;

    f32x4 acc[2][4];
#pragma unroll
    for (int i = 0; i < 2; ++i)
#pragma unroll
        for (int j = 0; j < 4; ++j) acc[i][j] = (f32x4){0.f, 0.f, 0.f, 0.f};

#pragma unroll
    for (int ks = 0; ks < 4; ++ks) {
        int k0 = ks * 32 + q * 8;
        half8 a0 = *(const half8*)(as_lds + (rr + m) * 136 + k0);
        half8 a1 = *(const half8*)(as_lds + (rr + 16 + m) * 136 + k0);
        half8 bf[4];
#pragma unroll
        for (int j = 0; j < 4; ++j)
            bf[j] = *(const half8*)(bs_lds + (cc + j * 16 + m) * 136 + k0);
#pragma unroll
        for (int j = 0; j < 4; ++j) {
            acc[0][j] = __builtin_amdgcn_mfma_f32_16x16x32_f16(a0, bf[j], acc[0][j], 0, 0, 0);
            acc[1][j] = __builtin_amdgcn_mfma_f32_16x16x32_f16(a1, bf[j], acc[1][j], 0, 0, 0);
        }
    }
    // epilogue: bias + relu, direct f32 stores (16-lane groups = full 64B lines)
    float bv[4];
#pragma unroll
    for (int j = 0; j < 4; ++j) bv[j] = bias[cc + j * 16 + m];
#pragma unroll
    for (int i = 0; i < 2; ++i)
#pragma unroll
        for (int g = 0; g < 4; ++g) {
            int row = row0 + rr + i * 16 + q * 4 + g;
            if (row < M) {
#pragma unroll
                for (int j = 0; j < 4; ++j)
                    Out[(size_t)row * 128 + cc + j * 16 + m] = fmaxf(acc[i][j][g] + bv[j], 0.f);
            }
        }
}

// ============================================================
// CSR build, atomic-free at global scope (counting sort, 2 levels).
// ============================================================

__global__ __launch_bounds__(256) void k_ph_hist(
    const int* __restrict__ dst, int* __restrict__ bh, int E, int chunk)
{
    __shared__ int hist[NB];
    int t = threadIdx.x;
    hist[t] = 0;
    __syncthreads();
    int e0 = blockIdx.x * chunk;
    int e1 = min(e0 + chunk, E);
    for (int e = e0 + t; e < e1; e += 256)
        atomicAdd(&hist[dst[e] >> BSH], 1);
    __syncthreads();
    bh[t * NBLK + blockIdx.x] = hist[t];
}

__global__ __launch_bounds__(1024) void k_ph_scan(int* __restrict__ bh)
{
    __shared__ int sd[1024];
    const int per = (NB * NBLK) / 1024;  // 64
    int t = threadIdx.x;
    int base = t * per;
    int loc[per];
    int sum = 0;
#pragma unroll
    for (int j = 0; j < per; ++j) { loc[j] = bh[base + j]; sum += loc[j]; }
    sd[t] = sum;
    __syncthreads();
    for (int o = 1; o < 1024; o <<= 1) {
        int x = (t >= o) ? sd[t - o] : 0;
        __syncthreads();
        sd[t] += x;
        __syncthreads();
    }
    int run = sd[t] - sum;
#pragma unroll
    for (int j = 0; j < per; ++j) { bh[base + j] = run; run += loc[j]; }
}

__global__ __launch_bounds__(256) void k_ph_bin(
    const int* __restrict__ ei, const int* __restrict__ bh,
    int2* __restrict__ binned, int E, int chunk)
{
    __shared__ int boff[NB];
    int t = threadIdx.x;
    boff[t] = bh[t * NBLK + blockIdx.x];
    __syncthreads();
    int e0 = blockIdx.x * chunk;
    int e1 = min(e0 + chunk, E);
    for (int e = e0 + t; e < e1; e += 256) {
        int s = ei[e];
        int d = ei[E + e];
        int p = atomicAdd(&boff[d >> BSH], 1);  // LDS atomic
        binned[p] = make_int2(s, d);
    }
}

__global__ __launch_bounds__(256) void k_ph_csr(
    const int2* __restrict__ binned, const int* __restrict__ bh,
    int* __restrict__ csr, int* __restrict__ off, int* __restrict__ deg,
    int N, int E)
{
    __shared__ int cnt[512], loff[512], sd[256];
    int b = blockIdx.x;
    int lo = b << BSH;
    if (lo >= N) return;
    int t = threadIdx.x;
    int seg = bh[b * NBLK];
    int segend = (b + 1 < NB) ? bh[(b + 1) * NBLK] : E;
    int len = segend - seg;
    cnt[t] = 0; cnt[t + 256] = 0;
    __syncthreads();
    for (int i = t; i < len; i += 256)
        atomicAdd(&cnt[binned[seg + i].y - lo], 1);
    __syncthreads();
    int a0 = cnt[2 * t], a1 = cnt[2 * t + 1];
    int s = a0 + a1;
    sd[t] = s;
    __syncthreads();
    for (int o = 1; o < 256; o <<= 1) {
        int x = (t >= o) ? sd[t - o] : 0;
        __syncthreads();
        sd[t] += x;
        __syncthreads();
    }
    int ex = sd[t] - s;
    loff[2 * t] = ex;
    loff[2 * t + 1] = ex + a0;
    int n0 = lo + 2 * t;
    if (n0 < N)     { off[n0] = seg + ex;          deg[n0] = a0; }
    if (n0 + 1 < N) { off[n0 + 1] = seg + ex + a0; deg[n0 + 1] = a1; }
    __syncthreads();
    for (int i = t; i < len; i += 256) {
        int2 e = binned[seg + i];
        int p = atomicAdd(&loff[e.y - lo], 1);  // LDS atomic
        csr[seg + p] = e.x;
    }
}

// ============================================================
// Gather/accumulate: one wave per destination node (unchanged).
// ============================================================

__global__ __launch_bounds__(256) void k_gather(
    const __half* __restrict__ Hh, const float* __restrict__ as_,
    const float* __restrict__ ad_, const int* __restrict__ off,
    const int* __restrict__ deg, const int* __restrict__ csr,
    __half* __restrict__ P, int N)
{
    __shared__ float ex_s[4][256];
    __shared__ int src_s[4][64];
    int wid = threadIdx.x >> 6;
    int lane = threadIdx.x & 63;
    int n = blockIdx.x * 4 + wid;
    if (n >= N) return;
    int dg = deg[n];
    int base = off[n];
    float4 adn = *(const float4*)(ad_ + (size_t)n * 4);
    int g = lane >> 4;
    int li = lane & 15;
    int hh = li >> 2;
    float s0 = 0.f, s1 = 0.f, s2 = 0.f, s3 = 0.f;
    float acc[8] = {0.f, 0.f, 0.f, 0.f, 0.f, 0.f, 0.f, 0.f};

    for (int c0 = 0; c0 < dg; c0 += 64) {
        int cnt = min(64, dg - c0);
        if (lane < cnt) {
            int se = csr[base + c0 + lane];
            float4 as = *(const float4*)(as_ + (size_t)se * 4);
            float e0 = as.x + adn.x, e1 = as.y + adn.y;
            float e2 = as.z + adn.z, e3 = as.w + adn.w;
            e0 = fmaxf(e0, 0.2f * e0); e1 = fmaxf(e1, 0.2f * e1);
            e2 = fmaxf(e2, 0.2f * e2); e3 = fmaxf(e3, 0.2f * e3);
            float x0 = __expf(e0), x1 = __expf(e1);
            float x2 = __expf(e2), x3 = __expf(e3);
            s0 += x0; s1 += x1; s2 += x2; s3 += x3;
            *(float4*)&ex_s[wid][lane * 4] = make_float4(x0, x1, x2, x3);
            src_s[wid][lane] = se;
        }
        __asm__ volatile("s_waitcnt lgkmcnt(0)" ::: "memory");
        int iters = (cnt + 3) >> 2;
        for (int ii = 0; ii < iters; ++ii) {
            int j = ii * 4 + g;
            bool valid = j < cnt;
            float w = valid ? ex_s[wid][j * 4 + hh] : 0.f;
            int se = valid ? src_s[wid][j] : 0;
            float4 raw = *(const float4*)(Hh + (size_t)se * 128 + li * 8);
            __half2* ph = (__half2*)&raw;
            float2 f0 = __half22float2(ph[0]);
            float2 f1 = __half22float2(ph[1]);
            float2 f2 = __half22float2(ph[2]);
            float2 f3 = __half22float2(ph[3]);
            acc[0] = fmaf(w, f0.x, acc[0]);
            acc[1] = fmaf(w, f0.y, acc[1]);
            acc[2] = fmaf(w, f1.x, acc[2]);
            acc[3] = fmaf(w, f1.y, acc[3]);
            acc[4] = fmaf(w, f2.x, acc[4]);
            acc[5] = fmaf(w, f2.y, acc[5]);
            acc[6] = fmaf(w, f3.x, acc[6]);
            acc[7] = fmaf(w, f3.y, acc[7]);
        }
        __asm__ volatile("s_waitcnt lgkmcnt(0)" ::: "memory");
    }

#pragma unroll
    for (int o = 1; o < 64; o <<= 1) {
        s0 += __shfl_xor(s0, o);
        s1 += __shfl_xor(s1, o);
        s2 += __shfl_xor(s2, o);
        s3 += __shfl_xor(s3, o);
    }
#pragma unroll
    for (int o = 16; o < 64; o <<= 1)
#pragma unroll
        for (int c = 0; c < 8; ++c) acc[c] += __shfl_xor(acc[c], o);

    float sh = (hh == 0) ? s0 : (hh == 1) ? s1 : (hh == 2) ? s2 : s3;
    float inv = 1.f / (sh + 1e-16f);
    if (g == 0) {
        __half2 o4[4];
#pragma unroll
        for (int k = 0; k < 4; ++k)
            o4[k] = __float22half2_rn(make_float2(acc[2 * k] * inv, acc[2 * k + 1] * inv));
        *(float4*)(P + (size_t)n * 128 + li * 8) = *(float4*)o4;
    }
}

// ============================================================

extern "C" void kernel_launch(void* const* d_in, const int* in_sizes, int n_in,
                              void* d_out, int out_size, void* d_ws, size_t ws_size,
                              hipStream_t stream)
{
    const float* x     = (const float*)d_in[0];
    const int*   ei    = (const int*)d_in[1];
    const float* W     = (const float*)d_in[2];
    const float* att_s = (const float*)d_in[3];
    const float* att_d = (const float*)d_in[4];
    const float* lin_w = (const float*)d_in[5];
    const float* lin_b = (const float*)d_in[6];
    float* out = (float*)d_out;
    int N = in_sizes[0] / 128;
    int E = in_sizes[1] / 2;

    char* p = (char*)d_ws;
    auto alloc = [&](size_t bytes) { char* r = p; p += (bytes + 255) & ~(size_t)255; return r; };
    f16*    Hh   = (f16*)alloc((size_t)N * 128 * 2);
    f16*    P    = (f16*)alloc((size_t)N * 128 * 2);
    float*  AS   = (float*)alloc((size_t)N * 4 * 4);
    float*  AD   = (float*)alloc((size_t)N * 4 * 4);
    int*    deg  = (int*)alloc((size_t)N * 4);
    int*    off  = (int*)alloc((size_t)N * 4);
    int*    csr  = (int*)alloc((size_t)E * 4);
    int2*   binned = (int2*)alloc((size_t)E * 8);
    int*    bh   = (int*)alloc((size_t)NB * NBLK * 4);

    int chunk = (E + NBLK - 1) / NBLK;
    int mb = (N + 63) / 64;
    k_gemm_att<<<mb, 256, 0, stream>>>(x, W, att_s, att_d, Hh, AS, AD, N);
    k_ph_hist<<<NBLK, 256, 0, stream>>>(ei + E, bh, E, chunk);
    k_ph_scan<<<1, 1024, 0, stream>>>(bh);
    k_ph_bin<<<NBLK, 256, 0, stream>>>(ei, bh, binned, E, chunk);
    k_ph_csr<<<NB, 256, 0, stream>>>(binned, bh, csr, off, deg, N, E);
    k_gather<<<(N + 3) / 4, 256, 0, stream>>>((const __half*)Hh, AS, AD, off, deg, csr, (__half*)P, N);
    k_gemm_bias_relu<<<mb, 256, 0, stream>>>(P, lin_w, lin_b, out, N);
}

// Round 7
// 303.919 us; speedup vs baseline: 1.6105x; 1.0025x over previous
//
#include <hip/hip_runtime.h>
#include <hip/hip_fp16.h>

#define NB   256   // dst buckets (512 nodes each), bucket = dst >> 9
#define NBLK 256   // blocks in phases A/C
#define BSH  9

typedef _Float16 f16;
typedef _Float16 half8 __attribute__((ext_vector_type(8)));
typedef __fp16 pk16x2 __attribute__((ext_vector_type(2)));  // cvt_pkrtz return type
typedef float f32x4 __attribute__((ext_vector_type(4)));

// ============================================================
// Prep: transpose W [k][n] f32 -> Wt [n][k] f16 (and lin_w -> LWt).
// 64 KB total, L2-resident; lets GEMM waves load B-frags straight
// from global with no LDS transpose staging.
// ============================================================
__global__ void k_prep(const float* __restrict__ W, const float* __restrict__ LW,
                       f16* __restrict__ Wt, f16* __restrict__ LWt)
{
    int n = blockIdx.x & 127;
    const float* src = (blockIdx.x < 128) ? W : LW;
    f16* dst = (blockIdx.x < 128) ? Wt : LWt;
    int k = threadIdx.x;  // 128 threads
    dst[n * 128 + k] = (f16)src[k * 128 + n];
}

// ============================================================
// MFMA GEMM 1: H = x @ W (f32 in -> fp16 compute, f32 acc, fp16 out)
// + attention-logit epilogue. Tile 64x128, 4 waves.
// A via LDS (pkrtz-converted); B-frags direct from global Wt [n][k] f16.
// Frag maps (m89/m120-verified): A[m=lane&15][k=quad*8+j],
// B[k=quad*8+j][n=lane&15], C/D col=lane&15 row=quad*4+reg.
// ============================================================
__global__ __launch_bounds__(256) void k_gemm_att(
    const float* __restrict__ A, const f16* __restrict__ Wt,
    const float* __restrict__ att_s, const float* __restrict__ att_d,
    f16* __restrict__ Hh, float* __restrict__ as_out, float* __restrict__ ad_out,
    int M)
{
    __shared__ __align__(16) f16 as_lds[64 * 136];
    int t = threadIdx.x;
    int row0 = blockIdx.x * 64;

    // Stage A: f32 -> f16 packed, [m][k] stride 136
    {
        int r = t >> 2, kq = (t & 3) * 32;
        const float* ap = A + (size_t)(row0 + r) * 128 + kq;
        bool valid = (row0 + r) < M;
        pk16x2 hb[16];
#pragma unroll
        for (int j = 0; j < 8; ++j) {
            float4 v = valid ? *(const float4*)(ap + j * 4) : make_float4(0.f, 0.f, 0.f, 0.f);
            hb[2 * j]     = __builtin_amdgcn_cvt_pkrtz(v.x, v.y);
            hb[2 * j + 1] = __builtin_amdgcn_cvt_pkrtz(v.z, v.w);
        }
        f16* dst = as_lds + r * 136 + kq;
#pragma unroll
        for (int j = 0; j < 4; ++j) *(float4*)(dst + j * 8) = ((float4*)hb)[j];
    }
    __syncthreads();

    int w = t >> 6, ln = t & 63;
    int rr = (w & 1) * 32;
    int cc = (w >> 1) * 64;
    int q = ln >> 4, m = ln & 15;

    f32x4 acc[2][4];
#pragma unroll
    for (int i = 0; i < 2; ++i)
#pragma unroll
        for (int j = 0; j < 4; ++j) acc[i][j] = (f32x4){0.f, 0.f, 0.f, 0.f};

    const f16* wp = Wt + (size_t)(cc + m) * 128 + q * 8;
#pragma unroll
    for (int ks = 0; ks < 4; ++ks) {
        int k0 = ks * 32 + q * 8;
        half8 a0 = *(const half8*)(as_lds + (rr + m) * 136 + k0);
        half8 a1 = *(const half8*)(as_lds + (rr + 16 + m) * 136 + k0);
        half8 bf[4];
#pragma unroll
        for (int j = 0; j < 4; ++j)
            bf[j] = *(const half8*)(wp + j * 16 * 128 + ks * 32);
#pragma unroll
        for (int j = 0; j < 4; ++j) {
            acc[0][j] = __builtin_amdgcn_mfma_f32_16x16x32_f16(a0, bf[j], acc[0][j], 0, 0, 0);
            acc[1][j] = __builtin_amdgcn_mfma_f32_16x16x32_f16(a1, bf[j], acc[1][j], 0, 0, 0);
        }
    }
    __syncthreads();
    // acc -> epilogue tile (reuse as_lds) [row][col] f16 stride 136
#pragma unroll
    for (int i = 0; i < 2; ++i)
#pragma unroll
        for (int j = 0; j < 4; ++j)
#pragma unroll
            for (int g = 0; g < 4; ++g)
                as_lds[(rr + i * 16 + q * 4 + g) * 136 + cc + j * 16 + m] = (f16)acc[i][j][g];
    __syncthreads();
    // coalesced H write
    {
        int r = t >> 2, cq = (t & 3) * 32;
        if (row0 + r < M) {
            float4 o0 = *(const float4*)(as_lds + r * 136 + cq);
            float4 o1 = *(const float4*)(as_lds + r * 136 + cq + 8);
            float4 o2 = *(const float4*)(as_lds + r * 136 + cq + 16);
            float4 o3 = *(const float4*)(as_lds + r * 136 + cq + 24);
            float4* hp = (float4*)(Hh + (size_t)(row0 + r) * 128 + cq);
            hp[0] = o0; hp[1] = o1; hp[2] = o2; hp[3] = o3;
        }
    }
    // attention dots: wave w rows w*16..+15; lane (q,m): row w*16+m, head q
    {
        int rl = w * 16 + m;
        int head = q;
        float ds = 0.f, dd = 0.f;
#pragma unroll
        for (int ch = 0; ch < 4; ++ch) {
            half8 hv = *(const half8*)(as_lds + rl * 136 + head * 32 + ch * 8);
            float4 s0 = *(const float4*)(att_s + head * 32 + ch * 8);
            float4 s1 = *(const float4*)(att_s + head * 32 + ch * 8 + 4);
            float4 d0 = *(const float4*)(att_d + head * 32 + ch * 8);
            float4 d1 = *(const float4*)(att_d + head * 32 + ch * 8 + 4);
            ds += (float)hv[0] * s0.x + (float)hv[1] * s0.y + (float)hv[2] * s0.z + (float)hv[3] * s0.w
                + (float)hv[4] * s1.x + (float)hv[5] * s1.y + (float)hv[6] * s1.z + (float)hv[7] * s1.w;
            dd += (float)hv[0] * d0.x + (float)hv[1] * d0.y + (float)hv[2] * d0.z + (float)hv[3] * d0.w
                + (float)hv[4] * d1.x + (float)hv[5] * d1.y + (float)hv[6] * d1.z + (float)hv[7] * d1.w;
        }
        if (row0 + rl < M) {
            as_out[(row0 + rl) * 4 + head] = ds;
            ad_out[(row0 + rl) * 4 + head] = dd;
        }
    }
}

// ============================================================
// MFMA GEMM 2: Out = relu(P @ lin_w + b). A fp16 via LDS copy,
// B-frags direct from global LWt [n][k] f16.
// ============================================================
__global__ __launch_bounds__(256) void k_gemm_bias_relu(
    const f16* __restrict__ Ah, const f16* __restrict__ LWt,
    const float* __restrict__ bias, float* __restrict__ Out, int M)
{
    __shared__ __align__(16) f16 as_lds[64 * 136];
    int t = threadIdx.x;
    int row0 = blockIdx.x * 64;
    {
        int r = t >> 2, kq = (t & 3) * 32;
        f16* dst = as_lds + r * 136 + kq;
        if (row0 + r < M) {
            const float4* ap = (const float4*)(Ah + (size_t)(row0 + r) * 128 + kq);
#pragma unroll
            for (int j = 0; j < 4; ++j) *(float4*)(dst + j * 8) = ap[j];
        } else {
            float4 z = make_float4(0.f, 0.f, 0.f, 0.f);
#pragma unroll
            for (int j = 0; j < 4; ++j) *(float4*)(dst + j * 8) = z;
        }
    }
    __syncthreads();

    int w = t >> 6, ln = t & 63;
    int rr = (w & 1) * 32;
    int cc = (w >> 1) * 64;
    int q = ln >> 4, m = ln & 15;

    f32x4 acc[2][4];
#pragma unroll
    for (int i = 0; i < 2; ++i)
#pragma unroll
        for (int j = 0; j < 4; ++j) acc[i][j] = (f32x4){0.f, 0.f, 0.f, 0.f};

    const f16* wp = LWt + (size_t)(cc + m) * 128 + q * 8;
#pragma unroll
    for (int ks = 0; ks < 4; ++ks) {
        int k0 = ks * 32 + q * 8;
        half8 a0 = *(const half8*)(as_lds + (rr + m) * 136 + k0);
        half8 a1 = *(const half8*)(as_lds + (rr + 16 + m) * 136 + k0);
        half8 bf[4];
#pragma unroll
        for (int j = 0; j < 4; ++j)
            bf[j] = *(const half8*)(wp + j * 16 * 128 + ks * 32);
#pragma unroll
        for (int j = 0; j < 4; ++j) {
            acc[0][j] = __builtin_amdgcn_mfma_f32_16x16x32_f16(a0, bf[j], acc[0][j], 0, 0, 0);
            acc[1][j] = __builtin_amdgcn_mfma_f32_16x16x32_f16(a1, bf[j], acc[1][j], 0, 0, 0);
        }
    }
    float bv[4];
#pragma unroll
    for (int j = 0; j < 4; ++j) bv[j] = bias[cc + j * 16 + m];
#pragma unroll
    for (int i = 0; i < 2; ++i)
#pragma unroll
        for (int g = 0; g < 4; ++g) {
            int row = row0 + rr + i * 16 + q * 4 + g;
            if (row < M) {
#pragma unroll
                for (int j = 0; j < 4; ++j)
                    Out[(size_t)row * 128 + cc + j * 16 + m] = fmaxf(acc[i][j][g] + bv[j], 0.f);
            }
        }
}

// ============================================================
// CSR build, atomic-free at global scope (counting sort, 2 levels).
// binned entry packed: src (17b) | dst-low-9 << 17  (N < 2^17).
// ============================================================

__global__ __launch_bounds__(256) void k_ph_hist(
    const int* __restrict__ dst, int* __restrict__ bh, int E, int chunk)
{
    __shared__ int hist[NB];
    int t = threadIdx.x;
    hist[t] = 0;
    __syncthreads();
    int e0 = blockIdx.x * chunk;
    int e1 = min(e0 + chunk, E);
    for (int e = e0 + t; e < e1; e += 256)
        atomicAdd(&hist[dst[e] >> BSH], 1);
    __syncthreads();
    bh[t * NBLK + blockIdx.x] = hist[t];
}

__global__ __launch_bounds__(1024) void k_ph_scan(int* __restrict__ bh)
{
    __shared__ int sd[1024];
    const int per = (NB * NBLK) / 1024;  // 64
    int t = threadIdx.x;
    int base = t * per;
    int loc[per];
    int sum = 0;
#pragma unroll
    for (int j = 0; j < per; ++j) { loc[j] = bh[base + j]; sum += loc[j]; }
    sd[t] = sum;
    __syncthreads();
    for (int o = 1; o < 1024; o <<= 1) {
        int x = (t >= o) ? sd[t - o] : 0;
        __syncthreads();
        sd[t] += x;
        __syncthreads();
    }
    int run = sd[t] - sum;
#pragma unroll
    for (int j = 0; j < per; ++j) { bh[base + j] = run; run += loc[j]; }
}

__global__ __launch_bounds__(256) void k_ph_bin(
    const int* __restrict__ ei, const int* __restrict__ bh,
    int* __restrict__ binned, int E, int chunk)
{
    __shared__ int boff[NB];
    int t = threadIdx.x;
    boff[t] = bh[t * NBLK + blockIdx.x];
    __syncthreads();
    int e0 = blockIdx.x * chunk;
    int e1 = min(e0 + chunk, E);
    for (int e = e0 + t; e < e1; e += 256) {
        int s = ei[e];
        int d = ei[E + e];
        int p = atomicAdd(&boff[d >> BSH], 1);  // LDS atomic
        binned[p] = s | ((d & ((1 << BSH) - 1)) << 17);
    }
}

__global__ __launch_bounds__(256) void k_ph_csr(
    const int* __restrict__ binned, const int* __restrict__ bh,
    int* __restrict__ csr, int* __restrict__ off, int* __restrict__ deg,
    int N, int E)
{
    __shared__ int cnt[512], loff[512], sd[256];
    int b = blockIdx.x;
    int lo = b << BSH;
    if (lo >= N) return;
    int t = threadIdx.x;
    int seg = bh[b * NBLK];
    int segend = (b + 1 < NB) ? bh[(b + 1) * NBLK] : E;
    int len = segend - seg;
    cnt[t] = 0; cnt[t + 256] = 0;
    __syncthreads();
    for (int i = t; i < len; i += 256)
        atomicAdd(&cnt[(unsigned)binned[seg + i] >> 17], 1);
    __syncthreads();
    int a0 = cnt[2 * t], a1 = cnt[2 * t + 1];
    int s = a0 + a1;
    sd[t] = s;
    __syncthreads();
    for (int o = 1; o < 256; o <<= 1) {
        int x = (t >= o) ? sd[t - o] : 0;
        __syncthreads();
        sd[t] += x;
        __syncthreads();
    }
    int ex = sd[t] - s;
    loff[2 * t] = ex;
    loff[2 * t + 1] = ex + a0;
    int n0 = lo + 2 * t;
    if (n0 < N)     { off[n0] = seg + ex;          deg[n0] = a0; }
    if (n0 + 1 < N) { off[n0 + 1] = seg + ex + a0; deg[n0 + 1] = a1; }
    __syncthreads();
    for (int i = t; i < len; i += 256) {
        int v = binned[seg + i];
        int p = atomicAdd(&loff[(unsigned)v >> 17], 1);  // LDS atomic
        csr[seg + p] = v & 0x1ffff;
    }
}

// ============================================================
// Gather/accumulate: one wave per destination node.
// Weight phase: zero-pad to 64 lanes, store per-head __half2 splat
// weights (removes per-edge validity + f16 convert from main loop).
// Main loop: v_pk_fma_f16 accumulate, f32 flush every 8 edges/lane.
// ============================================================
__global__ __launch_bounds__(256) void k_gather(
    const __half* __restrict__ Hh, const float* __restrict__ as_,
    const float* __restrict__ ad_, const int* __restrict__ off,
    const int* __restrict__ deg, const int* __restrict__ csr,
    __half* __restrict__ P, int N)
{
    __shared__ __half2 exh[4][4][68];  // [wave][head][edge] (pad 68: no bank conflict)
    __shared__ int src_s[4][64];
    int wid = threadIdx.x >> 6;
    int lane = threadIdx.x & 63;
    int n = blockIdx.x * 4 + wid;
    if (n >= N) return;
    int dg = deg[n];
    int base = off[n];
    float4 adn = *(const float4*)(ad_ + (size_t)n * 4);
    int g = lane >> 4;        // edge sub-slot 0..3
    int li = lane & 15;       // channel group: channels li*8..+7
    int hh = li >> 2;         // head of this channel group
    float s0 = 0.f, s1 = 0.f, s2 = 0.f, s3 = 0.f;
    float acc[8] = {0.f, 0.f, 0.f, 0.f, 0.f, 0.f, 0.f, 0.f};

    for (int c0 = 0; c0 < dg; c0 += 64) {
        int cnt = min(64, dg - c0);
        // weight phase: all 64 lanes store (zero weight for pad lanes)
        {
            int idx = c0 + lane;
            int se = csr[base + min(idx, dg - 1)];
            float4 as = *(const float4*)(as_ + (size_t)se * 4);
            float e0 = as.x + adn.x, e1 = as.y + adn.y;
            float e2 = as.z + adn.z, e3 = as.w + adn.w;
            e0 = fmaxf(e0, 0.2f * e0); e1 = fmaxf(e1, 0.2f * e1);
            e2 = fmaxf(e2, 0.2f * e2); e3 = fmaxf(e3, 0.2f * e3);
            float x0 = __expf(e0), x1 = __expf(e1);
            float x2 = __expf(e2), x3 = __expf(e3);
            if (idx >= dg) { x0 = x1 = x2 = x3 = 0.f; }
            s0 += x0; s1 += x1; s2 += x2; s3 += x3;
            exh[wid][0][lane] = __float2half2_rn(x0);
            exh[wid][1][lane] = __float2half2_rn(x1);
            exh[wid][2][lane] = __float2half2_rn(x2);
            exh[wid][3][lane] = __float2half2_rn(x3);
            src_s[wid][lane] = se;
        }
        __asm__ volatile("s_waitcnt lgkmcnt(0)" ::: "memory");
        int iters = (cnt + 3) >> 2;
        __half2 ah[4];
        ah[0] = ah[1] = ah[2] = ah[3] = __float2half2_rn(0.f);
        for (int ii = 0; ii < iters; ++ii) {
            int j = ii * 4 + g;          // j < 64 always; pad edges have w=0
            __half2 w2 = exh[wid][hh][j];
            int se = src_s[wid][j];
            float4 raw = *(const float4*)(Hh + (size_t)se * 128 + li * 8);
            __half2* ph = (__half2*)&raw;
            ah[0] = __hfma2(ph[0], w2, ah[0]);
            ah[1] = __hfma2(ph[1], w2, ah[1]);
            ah[2] = __hfma2(ph[2], w2, ah[2]);
            ah[3] = __hfma2(ph[3], w2, ah[3]);
            if ((ii & 7) == 7) {  // f32 flush every 8 edges/lane
#pragma unroll
                for (int k = 0; k < 4; ++k) {
                    float2 f = __half22float2(ah[k]);
                    acc[2 * k] += f.x; acc[2 * k + 1] += f.y;
                    ah[k] = __float2half2_rn(0.f);
                }
            }
        }
#pragma unroll
        for (int k = 0; k < 4; ++k) {  // tail flush (chunk end)
            float2 f = __half22float2(ah[k]);
            acc[2 * k] += f.x; acc[2 * k + 1] += f.y;
        }
        __asm__ volatile("s_waitcnt lgkmcnt(0)" ::: "memory");
    }

    // softmax denominators
#pragma unroll
    for (int o = 1; o < 64; o <<= 1) {
        s0 += __shfl_xor(s0, o);
        s1 += __shfl_xor(s1, o);
        s2 += __shfl_xor(s2, o);
        s3 += __shfl_xor(s3, o);
    }
    // combine the 4 edge sub-slots
#pragma unroll
    for (int o = 16; o < 64; o <<= 1)
#pragma unroll
        for (int c = 0; c < 8; ++c) acc[c] += __shfl_xor(acc[c], o);

    float sh = (hh == 0) ? s0 : (hh == 1) ? s1 : (hh == 2) ? s2 : s3;
    float inv = 1.f / (sh + 1e-16f);
    if (g == 0) {
        __half2 o4[4];
#pragma unroll
        for (int k = 0; k < 4; ++k)
            o4[k] = __float22half2_rn(make_float2(acc[2 * k] * inv, acc[2 * k + 1] * inv));
        *(float4*)(P + (size_t)n * 128 + li * 8) = *(float4*)o4;
    }
}

// ============================================================

extern "C" void kernel_launch(void* const* d_in, const int* in_sizes, int n_in,
                              void* d_out, int out_size, void* d_ws, size_t ws_size,
                              hipStream_t stream)
{
    const float* x     = (const float*)d_in[0];
    const int*   ei    = (const int*)d_in[1];
    const float* W     = (const float*)d_in[2];
    const float* att_s = (const float*)d_in[3];
    const float* att_d = (const float*)d_in[4];
    const float* lin_w = (const float*)d_in[5];
    const float* lin_b = (const float*)d_in[6];
    float* out = (float*)d_out;
    int N = in_sizes[0] / 128;
    int E = in_sizes[1] / 2;

    char* p = (char*)d_ws;
    auto alloc = [&](size_t bytes) { char* r = p; p += (bytes + 255) & ~(size_t)255; return r; };
    f16*    Hh   = (f16*)alloc((size_t)N * 128 * 2);
    f16*    P    = (f16*)alloc((size_t)N * 128 * 2);
    f16*    Wt   = (f16*)alloc(128 * 128 * 2);
    f16*    LWt  = (f16*)alloc(128 * 128 * 2);
    float*  AS   = (float*)alloc((size_t)N * 4 * 4);
    float*  AD   = (float*)alloc((size_t)N * 4 * 4);
    int*    deg  = (int*)alloc((size_t)N * 4);
    int*    off  = (int*)alloc((size_t)N * 4);
    int*    csr  = (int*)alloc((size_t)E * 4);
    int*    binned = (int*)alloc((size_t)E * 4);
    int*    bh   = (int*)alloc((size_t)NB * NBLK * 4);

    int chunk = (E + NBLK - 1) / NBLK;
    int mb = (N + 63) / 64;
    k_prep<<<256, 128, 0, stream>>>(W, lin_w, Wt, LWt);
    k_gemm_att<<<mb, 256, 0, stream>>>(x, Wt, att_s, att_d, Hh, AS, AD, N);
    k_ph_hist<<<NBLK, 256, 0, stream>>>(ei + E, bh, E, chunk);
    k_ph_scan<<<1, 1024, 0, stream>>>(bh);
    k_ph_bin<<<NBLK, 256, 0, stream>>>(ei, bh, binned, E, chunk);
    k_ph_csr<<<NB, 256, 0, stream>>>(binned, bh, csr, off, deg, N, E);
    k_gather<<<(N + 3) / 4, 256, 0, stream>>>((const __half*)Hh, AS, AD, off, deg, csr, (__half*)P, N);
    k_gemm_bias_relu<<<mb, 256, 0, stream>>>(P, LWt, lin_b, out, N);
}